// Round 18
// baseline (124.084 us; speedup 1.0000x reference)
//
#include <hip/hip_runtime.h>

// BIATT: B=16, Lc=Lp=1024, D=128, H=4, PFEAT=1024. All inputs fp32.
// Algebra: cv is rank-1 (c[b,l]*cp[d]) => A = tanh(c[b,l]*g[b,h,m]);
// scores reduce to 1D sums over tanh of an outer product.
// KA: param folds + transposes. KB: pv GEMM (split-bf16, K-split x2) UNION
// c-side maps. KC: weight-stationary 3-term split + g -- R18: single 17.4KB
// LDS buffer, 4 stage phases (hi0,lo0,hi1,lo1) -> 8 blocks/CU (was 4).
// KD: fused tile tanh reduction (T packed bf16). KE: softmax+pools. KF: finals.

using bf16x8 = __attribute__((ext_vector_type(8))) short;
using u16x8  = __attribute__((ext_vector_type(8))) unsigned short;
using f32x4  = __attribute__((ext_vector_type(4))) float;

#define TWO_LOG2E 2.8853900817779268f

__device__ __forceinline__ float exp2_raw(float x){
#if __has_builtin(__builtin_amdgcn_exp2f)
  return __builtin_amdgcn_exp2f(x);
#else
  float r; asm("v_exp_f32 %0, %1" : "=v"(r) : "v"(x)); return r;
#endif
}
__device__ __forceinline__ float tanh_fast(float x){
  float e = exp2_raw(x * TWO_LOG2E);
  return fmaf(-2.0f, __builtin_amdgcn_rcpf(e + 1.0f), 1.0f);
}
__device__ __forceinline__ unsigned short f2bf(float f){
  unsigned u = __float_as_uint(f);
  u = (u + 0x7FFFu + ((u >> 16) & 1u)) >> 16; // RNE
  return (unsigned short)u;
}
__device__ __forceinline__ float bf2f(unsigned short s){
  return __uint_as_float((unsigned)s << 16);
}
__device__ __forceinline__ unsigned cvt_pk_bf16(float a, float b){
  unsigned r;
  asm("v_cvt_pk_bf16_f32 %0, %1, %2" : "=v"(r) : "v"(a), "v"(b));
  return r;
}
// split 8 f32 -> hi/lo bf16x8 fragments (lo = x - hi is exact in f32)
__device__ __forceinline__ void split8(const float4& x, const float4& y, bf16x8& hi, bf16x8& lo){
  unsigned h0 = cvt_pk_bf16(x.x, x.y);
  unsigned h1 = cvt_pk_bf16(x.z, x.w);
  unsigned h2 = cvt_pk_bf16(y.x, y.y);
  unsigned h3 = cvt_pk_bf16(y.z, y.w);
  float r0 = x.x - __uint_as_float(h0 << 16);
  float r1 = x.y - __uint_as_float(h0 & 0xffff0000u);
  float r2 = x.z - __uint_as_float(h1 << 16);
  float r3 = x.w - __uint_as_float(h1 & 0xffff0000u);
  float r4 = y.x - __uint_as_float(h2 << 16);
  float r5 = y.y - __uint_as_float(h2 & 0xffff0000u);
  float r6 = y.z - __uint_as_float(h3 << 16);
  float r7 = y.w - __uint_as_float(h3 & 0xffff0000u);
  uint4 H = make_uint4(h0, h1, h2, h3);
  uint4 L = make_uint4(cvt_pk_bf16(r0, r1), cvt_pk_bf16(r2, r3),
                       cvt_pk_bf16(r4, r5), cvt_pk_bf16(r6, r7));
  hi = __builtin_bit_cast(bf16x8, H);
  lo = __builtin_bit_cast(bf16x8, L);
}

// ---------------------------------------------------------------- KA: param folds (bid<4) + transposes (bid>=4)
__global__ __launch_bounds__(256) void ka_prep(
    const float* __restrict__ c_param,
    const float* __restrict__ U, const float* __restrict__ W_comb_c,
    const float* __restrict__ Wh_c, const float* __restrict__ W_c2p,
    const float* __restrict__ p_param, const float* __restrict__ W_p2c,
    const float* __restrict__ Wh_p,
    float* __restrict__ uh, float* __restrict__ wccv,
    float* __restrict__ whc_v, float* __restrict__ wc2p_v,
    unsigned short* __restrict__ ppT_hi, unsigned short* __restrict__ ppT_lo,
    unsigned short* __restrict__ wp2cT_hi, unsigned short* __restrict__ wp2cT_lo,
    unsigned short* __restrict__ whpT_hi, unsigned short* __restrict__ whpT_lo)
{
  __shared__ float T[64*68];
  int bid0 = blockIdx.x, t = threadIdx.x;
  if (bid0 < 4) {
    int h = bid0;
    if (t < 128) {
      float s_uh = 0.f, s_wcc = 0.f, s_whc = 0.f, s_wc2p = 0.f;
      for (int d = 0; d < 128; ++d) {
        float cp = c_param[d];
        s_uh   += cp * U[(h*128 + d)*128 + t];
        s_wcc  += cp * W_comb_c[(h*128 + d)*128 + t];
        s_whc  += cp * Wh_c[(h*128 + d)*128 + t];
        s_wc2p += cp * W_c2p[(h*128 + d)*128 + t];
      }
      uh[h*128 + t]     = s_uh;
      wccv[h*128 + t]   = s_wcc;
      whc_v[h*128 + t]  = s_whc;
      wc2p_v[h*128 + t] = s_wc2p;
    }
    return;
  }
  int bid = bid0 - 4;
  const float* src; unsigned short* dh; unsigned short* dl;
  int k0, e0, dpitch, drow0;
  if (bid < 32) {
    k0 = (bid >> 1)*64; e0 = (bid & 1)*64;
    src = p_param; dh = ppT_hi; dl = ppT_lo; dpitch = 1024; drow0 = e0;
  } else if (bid < 48) {
    int w = bid - 32; int h = w >> 2, ki = (w >> 1) & 1, ej = w & 1;
    k0 = ki*64; e0 = ej*64;
    src = W_p2c + h*16384; dh = wp2cT_hi; dl = wp2cT_lo; dpitch = 128;
    drow0 = h*128 + e0;
  } else {
    int w = bid - 48; int h = w >> 2, ki = (w >> 1) & 1, ej = w & 1;
    k0 = ki*64; e0 = ej*64;
    src = Wh_p + h*16384; dh = whpT_hi; dl = whpT_lo; dpitch = 128;
    drow0 = h*128 + e0;
  }
  {
    int r = t >> 2, cs = (t & 3)*4;
    const float* s = src + (k0 + r)*128 + e0 + cs;
    #pragma unroll
    for (int j = 0; j < 4; ++j) {
      float4 v = *(const float4*)(s + j*16);
      *(float4*)&T[r*68 + cs + j*16] = v;
    }
  }
  __syncthreads();
  {
    int e = t >> 2, ks = (t & 3)*16;
    unsigned short hs[16], ls[16];
    #pragma unroll
    for (int j = 0; j < 16; ++j) {
      float v = T[(ks + j)*68 + e];
      unsigned short hh = f2bf(v);
      hs[j] = hh; ls[j] = f2bf(v - bf2f(hh));
    }
    unsigned short* ph = dh + (drow0 + e)*dpitch + k0 + ks;
    unsigned short* pl = dl + (drow0 + e)*dpitch + k0 + ks;
    *(u16x8*)ph       = *(u16x8*)&hs[0];
    *(u16x8*)(ph + 8) = *(u16x8*)&hs[8];
    *(u16x8*)pl       = *(u16x8*)&ls[0];
    *(u16x8*)(pl + 8) = *(u16x8*)&ls[8];
  }
}

// ---------------------------------------------------------------- KB: pv GEMM (bid<512, K-split x2) UNION c-side maps
__global__ __launch_bounds__(256) void kb_pv_maps(
    const float* __restrict__ p,
    const unsigned short* __restrict__ ppT_hi, const unsigned short* __restrict__ ppT_lo,
    float* __restrict__ pv_part0, float* __restrict__ pv_part1,
    const float* __restrict__ c, const float* __restrict__ c_mask,
    const float* __restrict__ whc_v, const float* __restrict__ wc2p_v,
    const float* __restrict__ bh_c, const float* __restrict__ b_c2p,
    const float* __restrict__ Wa_c, const float* __restrict__ Wa_p,
    const float* __restrict__ ba_c,
    float* __restrict__ score_c, float2* __restrict__ pairP)
{
  __shared__ __align__(16) char smem[36864];
  int bid = blockIdx.x, t = threadIdx.x;
  if (bid < 512) {
    short* Bh = (short*)smem;              // [128*72]
    short* Bl = (short*)(smem + 18432);
    int khalf = bid >> 8, rowtile = bid & 255;
    int kbase = khalf * 512;
    int row0 = rowtile * 64;
    float* __restrict__ pvp = khalf ? pv_part1 : pv_part0;
    int w = t >> 6, lane = t & 63;
    int l15 = lane & 15, l4 = lane >> 4;

    int bcol = t >> 1, bkh = (t & 1) * 32;
    const unsigned short* gBh = ppT_hi + bcol*1024 + kbase + bkh;
    const unsigned short* gBl = ppT_lo + bcol*1024 + kbase + bkh;
    short* sBh = &Bh[bcol*72 + bkh];
    short* sBl = &Bl[bcol*72 + bkh];

    const float* gA = p + (row0 + w*16 + l15)*1024 + kbase + l4*8;

    u16x8 rb[8];
    float4 ra[4];

    #pragma unroll
    for (int j = 0; j < 4; ++j) {
      rb[j]   = *(const u16x8*)(gBh + j*8);
      rb[4+j] = *(const u16x8*)(gBl + j*8);
    }
    #pragma unroll
    for (int j = 0; j < 4; ++j)
      ra[j] = *(const float4*)(gA + (j>>1)*32 + (j&1)*4);

    f32x4 acc[8];
    #pragma unroll
    for (int n = 0; n < 8; ++n) acc[n] = (f32x4){0.f,0.f,0.f,0.f};

    for (int kc = 0; kc < 8; ++kc) {
      __syncthreads();
      #pragma unroll
      for (int j = 0; j < 4; ++j) {
        *(u16x8*)(sBh + j*8) = rb[j];
        *(u16x8*)(sBl + j*8) = rb[4+j];
      }
      if (kc < 7) {
        #pragma unroll
        for (int j = 0; j < 4; ++j) {
          rb[j]   = *(const u16x8*)(gBh + (kc+1)*64 + j*8);
          rb[4+j] = *(const u16x8*)(gBl + (kc+1)*64 + j*8);
        }
      }
      float4 ran0, ran1, ran2, ran3;
      if (kc < 7) {
        const float* gAn = gA + (kc+1)*64;
        ran0 = *(const float4*)(gAn);
        ran1 = *(const float4*)(gAn + 4);
        ran2 = *(const float4*)(gAn + 32);
        ran3 = *(const float4*)(gAn + 36);
      }
      __syncthreads();
      #pragma unroll
      for (int ks = 0; ks < 2; ++ks) {
        bf16x8 ah, al;
        split8(ra[2*ks], ra[2*ks+1], ah, al);
        #pragma unroll
        for (int ct = 0; ct < 8; ++ct) {
          bf16x8 bh = *(const bf16x8*)&Bh[(ct*16 + l15)*72 + ks*32 + l4*8];
          bf16x8 bl = *(const bf16x8*)&Bl[(ct*16 + l15)*72 + ks*32 + l4*8];
          acc[ct] = __builtin_amdgcn_mfma_f32_16x16x32_bf16(ah, bh, acc[ct], 0, 0, 0);
          acc[ct] = __builtin_amdgcn_mfma_f32_16x16x32_bf16(ah, bl, acc[ct], 0, 0, 0);
          acc[ct] = __builtin_amdgcn_mfma_f32_16x16x32_bf16(al, bh, acc[ct], 0, 0, 0);
        }
      }
      if (kc < 7) { ra[0] = ran0; ra[1] = ran1; ra[2] = ran2; ra[3] = ran3; }
    }

    #pragma unroll
    for (int ct = 0; ct < 8; ++ct) {
      int col = ct*16 + l15;
      #pragma unroll
      for (int r = 0; r < 4; ++r) {
        int row = row0 + w*16 + l4*4 + r;
        pvp[row*128 + col] = acc[ct][r];
      }
    }
  } else {
    float* fsh = (float*)smem;  // 6 x 128 floats
    float* whc_l  = fsh;
    float* wc2p_l = fsh + 128;
    float* bhc_l  = fsh + 256;
    float* bc2p_l = fsh + 384;
    float* wac1_l = fsh + 512;
    float* wap2_l = fsh + 640;
    int i = bid - 512;
    int b = i >> 4, h = (i >> 2) & 3, lc = i & 3;
    if (t < 128) {
      whc_l[t]  = whc_v[h*128 + t];
      wc2p_l[t] = wc2p_v[h*128 + t];
      bhc_l[t]  = bh_c[h*128 + t];
      bc2p_l[t] = b_c2p[h*128 + t];
      wac1_l[t] = Wa_c[h*256 + t];
      wap2_l[t] = Wa_p[h*256 + 128 + t];
    }
    __syncthreads();
    int l = lc*256 + t;
    float cl = c[b*1024 + l];
    float a1 = 0.f, a2 = 0.f;
    #pragma unroll 4
    for (int e = 0; e < 128; ++e) {
      a1 += wac1_l[e] * tanh_fast(cl*whc_l[e]  + bhc_l[e]);
      a2 += wap2_l[e] * tanh_fast(cl*wc2p_l[e] + bc2p_l[e]);
    }
    int o = (b*4 + h)*1024 + l;
    score_c[o] = a1 + ba_c[h];
    pairP[o] = make_float2(TWO_LOG2E * cl, c_mask[b*1024 + l] * a2);
  }
}

// ---------------------------------------------------------------- KC: weight-stationary per-(path,h), 3-term split + g
// grid 2048: bid = ph*256 + mtile (64 rows). Single 17.4 KB LDS buffer,
// 4 stage phases (hi[0:64], lo[0:64], hi[64:128], lo[64:128]) -> 8 blocks/CU.
__global__ __launch_bounds__(256) void kc_head(
    const float* __restrict__ pv0, const float* __restrict__ pv1,
    const unsigned short* __restrict__ wp2cT_hi, const unsigned short* __restrict__ wp2cT_lo,
    const unsigned short* __restrict__ whpT_hi, const unsigned short* __restrict__ whpT_lo,
    const float* __restrict__ b_p2c, const float* __restrict__ bh_p,
    const float* __restrict__ Wa_c, const float* __restrict__ Wa_p,
    const float* __restrict__ p_mask, const float* __restrict__ ba_p,
    const float* __restrict__ uh,
    float2* __restrict__ pairC, float* __restrict__ score_p,
    float* __restrict__ g_arr, float* __restrict__ pv_sum)
{
  __shared__ __align__(16) short Wbuf[64*136];
  int t = threadIdx.x;
  int bid = blockIdx.x;
  int ph = bid >> 8, mtile = bid & 255;
  int path = ph >> 2, h = ph & 3;
  int w = t >> 6, lane = t & 63;
  int l15 = lane & 15, l4 = lane >> 4;

  const unsigned short* Wgh = (path ? whpT_hi : wp2cT_hi) + h*16384;
  const unsigned short* Wgl = (path ? whpT_lo : wp2cT_lo) + h*16384;
  int e2 = t >> 2, k0s = (t & 3)*32;
  // phase sources: 0: hi rows 0-63, 1: lo rows 0-63, 2: hi rows 64-127, 3: lo rows 64-127
  const unsigned short* psrc[4] = {
    Wgh + e2*128 + k0s,  Wgl + e2*128 + k0s,
    Wgh + (64 + e2)*128 + k0s,  Wgl + (64 + e2)*128 + k0s };

  // prefetch phase 0 into regs (overlaps A-load latency)
  u16x8 wr[4];
  {
    const u16x8* s = (const u16x8*)psrc[0];
    #pragma unroll
    for (int j = 0; j < 4; ++j) wr[j] = s[j];
  }

  const float* bias_g = path ? bh_p : b_p2c;
  float biasv[8], wav[8];
  #pragma unroll
  for (int n = 0; n < 8; ++n) {
    int col = n*16 + l15;
    biasv[n] = bias_g[h*128 + col];
    wav[n]   = path ? Wa_p[h*256 + col] : Wa_c[h*256 + 128 + col];
  }

  int rowbase = mtile*64 + w*16;
  bf16x8 afh[4], afl[4];
  float gacc = 0.f;
  {
    int off = (rowbase + l15)*128 + l4*8;
    #pragma unroll
    for (int kt = 0; kt < 4; ++kt) {
      float4 x0 = *(const float4*)(pv0 + off + kt*32);
      float4 y0 = *(const float4*)(pv0 + off + kt*32 + 4);
      float4 x1 = *(const float4*)(pv1 + off + kt*32);
      float4 y1 = *(const float4*)(pv1 + off + kt*32 + 4);
      float4 x = make_float4(x0.x+x1.x, x0.y+x1.y, x0.z+x1.z, x0.w+x1.w);
      float4 y = make_float4(y0.x+y1.x, y0.y+y1.y, y0.z+y1.z, y0.w+y1.w);
      if (ph == 0) {
        *(float4*)(pv_sum + off + kt*32)     = x;
        *(float4*)(pv_sum + off + kt*32 + 4) = y;
      }
      split8(x, y, afh[kt], afl[kt]);
      if (!path) {
        float4 u0 = *(const float4*)(uh + h*128 + kt*32 + l4*8);
        float4 u1 = *(const float4*)(uh + h*128 + kt*32 + l4*8 + 4);
        gacc += x.x*u0.x + x.y*u0.y + x.z*u0.z + x.w*u0.w
              + y.x*u1.x + y.y*u1.y + y.z*u1.z + y.w*u1.w;
      }
    }
  }
  if (!path) {
    float gg = gacc;
    gg += __shfl_xor(gg, 16, 64);
    gg += __shfl_xor(gg, 32, 64);
    if (l4 == 0) {
      int grow = rowbase + l15;
      int bb = grow >> 10, m = grow & 1023;
      int idx = (bb*4 + h)*1024 + m;
      g_arr[idx] = gg;
      pairC[idx].x = TWO_LOG2E * gg;
    }
  }

  f32x4 acc[8];
  #pragma unroll
  for (int n = 0; n < 8; ++n) acc[n] = (f32x4){0.f,0.f,0.f,0.f};

  // 4 phases: stage wr -> LDS, barrier, prefetch next, MFMA, barrier
  #pragma unroll
  for (int phx = 0; phx < 4; ++phx) {
    {
      u16x8* d = (u16x8*)&Wbuf[e2*136 + k0s];
      #pragma unroll
      for (int j = 0; j < 4; ++j) d[j] = wr[j];
    }
    __syncthreads();
    if (phx < 3) {
      const u16x8* s = (const u16x8*)psrc[phx + 1];
      #pragma unroll
      for (int j = 0; j < 4; ++j) wr[j] = s[j];
    }
    int nbase = (phx >> 1) * 4;       // cols 0-63 for phx 0,1; 64-127 for 2,3
    bool isHi = (phx & 1) == 0;
    #pragma unroll
    for (int n = 0; n < 4; ++n) {
      int nn = nbase + n;
      #pragma unroll
      for (int kt = 0; kt < 4; ++kt) {
        bf16x8 bf = *(const bf16x8*)&Wbuf[(n*16 + l15)*136 + kt*32 + l4*8];
        if (isHi) {
          acc[nn] = __builtin_amdgcn_mfma_f32_16x16x32_bf16(afh[kt], bf, acc[nn], 0, 0, 0);
          acc[nn] = __builtin_amdgcn_mfma_f32_16x16x32_bf16(afl[kt], bf, acc[nn], 0, 0, 0);
        } else {
          acc[nn] = __builtin_amdgcn_mfma_f32_16x16x32_bf16(afh[kt], bf, acc[nn], 0, 0, 0);
        }
      }
    }
    __syncthreads();
  }

  {
    float pp0 = 0.f, pp1 = 0.f, pp2 = 0.f, pp3 = 0.f;
    #pragma unroll
    for (int n = 0; n < 8; ++n) {
      float bb = biasv[n], ww = wav[n];
      pp0 += ww * tanh_fast(acc[n][0] + bb);
      pp1 += ww * tanh_fast(acc[n][1] + bb);
      pp2 += ww * tanh_fast(acc[n][2] + bb);
      pp3 += ww * tanh_fast(acc[n][3] + bb);
    }
    #pragma unroll
    for (int off = 1; off < 16; off <<= 1) {
      pp0 += __shfl_xor(pp0, off, 64);
      pp1 += __shfl_xor(pp1, off, 64);
      pp2 += __shfl_xor(pp2, off, 64);
      pp3 += __shfl_xor(pp3, off, 64);
    }
    if (l15 == 0) {
      int grow = rowbase + l4*4;
      int bb = grow >> 10, m = grow & 1023;
      int idx = (bb*4 + h)*1024 + m;
      if (path) {
        float bap = ba_p[h];
        *(float4*)&score_p[idx] = make_float4(pp0+bap, pp1+bap, pp2+bap, pp3+bap);
      } else {
        float4 mk = *(const float4*)&p_mask[bb*1024 + m];
        pairC[idx+0].y = mk.x * pp0;
        pairC[idx+1].y = mk.y * pp1;
        pairC[idx+2].y = mk.z * pp2;
        pairC[idx+3].y = mk.w * pp3;
      }
    }
  }
}

// ---------------------------------------------------------------- KD: fused tile tanh reduction (T as packed bf16)
// grid 8192: bid = bh*128 + tile; 128(l) x 64(m) per block.
__global__ __launch_bounds__(256) void kd_scores(
    const float* __restrict__ c_mask, const float* __restrict__ p_mask,
    const float* __restrict__ g_arr,
    const float2* __restrict__ pairC, const float2* __restrict__ pairP,
    float* __restrict__ score_c, float* __restrict__ score_p)
{
  __shared__ unsigned Tp[128*33];   // packed bf16 pairs, pitch 33 uints
  __shared__ float gm_s[64], ptw_s[64], pm_s[64];
  __shared__ float kl_s[128], ctw_s[128], cm_s[128];
  __shared__ float red[256];
  int bid = blockIdx.x, t = threadIdx.x;
  int bh = bid >> 7, tile = bid & 127;
  int b = bh >> 2;
  int l0 = (tile >> 4) * 128, m0 = (tile & 15) * 64;
  if (t < 64) {
    gm_s[t]  = g_arr[bh*1024 + m0 + t];
    ptw_s[t] = pairC[bh*1024 + m0 + t].y;
    pm_s[t]  = p_mask[b*1024 + m0 + t];
  } else if (t < 192) {
    int l = t - 64;
    float2 pp = pairP[bh*1024 + l0 + l];
    kl_s[l] = pp.x; ctw_s[l] = pp.y;
    cm_s[l] = c_mask[b*1024 + l0 + l];
  }
  __syncthreads();
  { // pass 1: 2 threads per l-row, 32 m each; pack bf16 pairs; rows -> score_c
    int r = t >> 1, hm = t & 1;
    float kl = kl_s[r];
    float accc = 0.f;
    #pragma unroll 4
    for (int j = 0; j < 32; j += 2) {
      int m = hm*32 + j;
      float e0 = exp2_raw(kl * gm_s[m]);
      float e1 = exp2_raw(kl * gm_s[m+1]);
      float t0 = fmaf(-2.0f, __builtin_amdgcn_rcpf(e0 + 1.0f), 1.0f);
      float t1 = fmaf(-2.0f, __builtin_amdgcn_rcpf(e1 + 1.0f), 1.0f);
      Tp[r*33 + hm*16 + (j>>1)] = cvt_pk_bf16(t0, t1);  // t0=low, t1=high
      accc = fmaf(ptw_s[m], t0, fmaf(ptw_s[m+1], t1, accc));
    }
    accc += __shfl_xor(accc, 1, 64);
    if (hm == 0) atomicAdd(score_c + bh*1024 + l0 + r, cm_s[r]*accc);
  }
  __syncthreads();
  { // pass 2: col = t&63, seg = t>>6; paired cols broadcast -> conflict-free
    int col = t & 63, seg = t >> 6;
    int ci = col >> 1, sel = col & 1;
    float accp = 0.f;
    #pragma unroll 8
    for (int j = 0; j < 32; ++j) {
      int l = seg*32 + j;
      unsigned pk = Tp[l*33 + ci];
      float tv = __uint_as_float(sel ? (pk & 0xffff0000u) : (pk << 16));
      accp = fmaf(ctw_s[l], tv, accp);
    }
    red[t] = accp;
    __syncthreads();
    if (t < 64) {
      float total = red[t] + red[t+64] + red[t+128] + red[t+192];
      atomicAdd(score_p + bh*1024 + m0 + t, pm_s[t]*total);
    }
  }
}

// ---------------------------------------------------------------- KE: softmax + pools (p-side 4-way chunked)
__device__ __forceinline__ float blk_red_max(float v, float* red, int t){
  red[t] = v; __syncthreads();
  for (int s = 128; s; s >>= 1) { if (t < s) red[t] = fmaxf(red[t], red[t+s]); __syncthreads(); }
  float r = red[0]; __syncthreads();
  return r;
}
__device__ __forceinline__ float blk_red_sum(float v, float* red, int t){
  red[t] = v; __syncthreads();
  for (int s = 128; s; s >>= 1) { if (t < s) red[t] += red[t+s]; __syncthreads(); }
  float r = red[0]; __syncthreads();
  return r;
}

__global__ __launch_bounds__(256) void ke_soft(
    const float* __restrict__ c, const float* __restrict__ c_mask, const float* __restrict__ p_mask,
    const float* __restrict__ score_c, const float* __restrict__ score_p,
    const float* __restrict__ pv_sum,
    float* __restrict__ s_c, float* __restrict__ pf_part)
{
  __shared__ float sv[1024];
  __shared__ float red[256];
  int bid = blockIdx.x, t = threadIdx.x;
  if (bid < 64) { // c-side
    int b = bid >> 2, h = bid & 3, bh = b*4 + h;
    const float* sc = score_c + bh*1024;
    const float* mk = c_mask + b*1024;
    float v[4];
    float mx = -1e30f;
    #pragma unroll
    for (int j = 0; j < 4; ++j) { v[j] = sc[t + j*256]; mx = fmaxf(mx, v[j]); }
    mx = blk_red_max(mx, red, t);
    float sum = 0.f;
    #pragma unroll
    for (int j = 0; j < 4; ++j) {
      float e = exp2_raw((v[j] - mx) * 1.4426950408889634f) * mk[t + j*256];
      sv[t + j*256] = e;
      sum += e;
    }
    sum = blk_red_sum(sum, red, t);
    float rinv = __fdividef(1.0f, sum + 1e-6f);
    float a = 0.f;
    #pragma unroll
    for (int j = 0; j < 4; ++j) a += sv[t + j*256] * rinv * c[b*1024 + t + j*256];
    a = blk_red_sum(a, red, t);
    if (t == 0) s_c[bh] = a;
  } else { // p-side, 4 chunks per (b,h)
    int i = bid - 64;
    int b = i >> 4, h = (i >> 2) & 3, ch = i & 3, bh = b*4 + h;
    const float* sc = score_p + bh*1024;
    const float* mk = p_mask + b*1024;
    float v[4];
    float mx = -1e30f;
    #pragma unroll
    for (int j = 0; j < 4; ++j) { v[j] = sc[t + j*256]; mx = fmaxf(mx, v[j]); }
    mx = blk_red_max(mx, red, t);
    float sum = 0.f;
    #pragma unroll
    for (int j = 0; j < 4; ++j) {
      float e = exp2_raw((v[j] - mx) * 1.4426950408889634f) * mk[t + j*256];
      sv[t + j*256] = e;
      sum += e;
    }
    sum = blk_red_sum(sum, red, t);
    float rinv = __fdividef(1.0f, sum + 1e-6f);
    int e0 = t & 127, seg = t >> 7;
    int mbase = ch*256 + seg*128;
    float acc = 0.f;
    const float* base = pv_sum + (b*1024 + mbase)*128 + e0;
    #pragma unroll 4
    for (int m = 0; m < 128; ++m) acc = fmaf(sv[mbase + m]*rinv, base[m*128], acc);
    red[t] = acc; __syncthreads();
    if (t < 128) pf_part[(ch*16 + b)*512 + h*128 + t] = red[t] + red[t + 128];
  }
}

// ---------------------------------------------------------------- KF: finals + outer product (sums pool chunks)
__global__ __launch_bounds__(256) void kf_final(
    const float* __restrict__ s_c, const float* __restrict__ wccv,
    const float* __restrict__ b_comb_c, const float* __restrict__ pf_part,
    const float* __restrict__ W_comb_p, const float* __restrict__ b_comb_p,
    float* __restrict__ out)
{
  __shared__ float pfr[512];
  __shared__ float cfl[128], pfl[128];
  int b = blockIdx.x, t = threadIdx.x;
  #pragma unroll
  for (int s = 0; s < 2; ++s) {
    int idx = t + s*256;
    pfr[idx] = pf_part[(0*16 + b)*512 + idx] + pf_part[(1*16 + b)*512 + idx]
             + pf_part[(2*16 + b)*512 + idx] + pf_part[(3*16 + b)*512 + idx];
  }
  __syncthreads();
  if (t < 128) {
    float cf = b_comb_c[t];
    #pragma unroll
    for (int h = 0; h < 4; ++h) cf += s_c[b*4 + h] * wccv[h*128 + t];
    float pf = b_comb_p[t];
    #pragma unroll 8
    for (int i = 0; i < 512; ++i) pf += pfr[i] * W_comb_p[i*128 + t];
    cfl[t] = cf; pfl[t] = pf;
  }
  __syncthreads();
  #pragma unroll
  for (int k = 0; k < 64; ++k) {
    int idx = k*256 + t;
    out[b*16384 + idx] = cfl[idx >> 7] * pfl[idx & 127];
  }
}

// ---------------------------------------------------------------- launcher
extern "C" void kernel_launch(void* const* d_in, const int* in_sizes, int n_in,
                              void* d_out, int out_size, void* d_ws, size_t ws_size,
                              hipStream_t stream)
{
  const float* c        = (const float*)d_in[0];
  const float* c_mask   = (const float*)d_in[1];
  const float* p        = (const float*)d_in[2];
  const float* p_mask   = (const float*)d_in[3];
  const float* c_param  = (const float*)d_in[4];
  const float* p_param  = (const float*)d_in[5];
  const float* U        = (const float*)d_in[6];
  const float* W_p2c    = (const float*)d_in[7];
  const float* b_p2c    = (const float*)d_in[8];
  const float* W_c2p    = (const float*)d_in[9];
  const float* b_c2p    = (const float*)d_in[10];
  const float* Wh_c     = (const float*)d_in[11];
  const float* bh_c     = (const float*)d_in[12];
  const float* Wh_p     = (const float*)d_in[13];
  const float* bh_p     = (const float*)d_in[14];
  const float* Wa_c     = (const float*)d_in[15];
  const float* ba_c     = (const float*)d_in[16];
  const float* Wa_p     = (const float*)d_in[17];
  const float* ba_p     = (const float*)d_in[18];
  const float* W_comb_c = (const float*)d_in[19];
  const float* b_comb_c = (const float*)d_in[20];
  const float* W_comb_p = (const float*)d_in[21];
  const float* b_comb_p = (const float*)d_in[22];
  float* out = (float*)d_out;

  char* ws = (char*)d_ws;
  float*          pv_part0 = (float*)         (ws + 0);
  float*          pv_part1 = (float*)         (ws + 8388608);
  float*          pv_sum   = (float*)         (ws + 16777216);
  unsigned short* ppT_hi   = (unsigned short*)(ws + 25165824);
  unsigned short* ppT_lo   = (unsigned short*)(ws + 25427968);
  unsigned short* wp2cT_hi = (unsigned short*)(ws + 25690112);
  unsigned short* wp2cT_lo = (unsigned short*)(ws + 25821184);
  unsigned short* whpT_hi  = (unsigned short*)(ws + 25952256);
  unsigned short* whpT_lo  = (unsigned short*)(ws + 26083328);
  float*          uh       = (float*)         (ws + 26214400);
  float*          wccv     = (float*)         (ws + 26216448);
  float*          whc_v    = (float*)         (ws + 26218496);
  float*          wc2p_v   = (float*)         (ws + 26220544);
  float*          g_arr    = (float*)         (ws + 26222592);
  float2*         pairC    = (float2*)        (ws + 26484736);
  float2*         pairP    = (float2*)        (ws + 27009024);
  float*          score_c  = (float*)         (ws + 27533312);
  float*          score_p  = (float*)         (ws + 27795456);
  float*          s_c      = (float*)         (ws + 28057600);
  float*          pf_part  = (float*)         (ws + 28057856);

  ka_prep<<<dim3(68), dim3(256), 0, stream>>>(
      c_param, U, W_comb_c, Wh_c, W_c2p, p_param, W_p2c, Wh_p,
      uh, wccv, whc_v, wc2p_v,
      ppT_hi, ppT_lo, wp2cT_hi, wp2cT_lo, whpT_hi, whpT_lo);

  kb_pv_maps<<<dim3(768), dim3(256), 0, stream>>>(
      p, ppT_hi, ppT_lo, pv_part0, pv_part1,
      c, c_mask, whc_v, wc2p_v, bh_c, b_c2p, Wa_c, Wa_p, ba_c,
      score_c, pairP);

  kc_head<<<dim3(2048), dim3(256), 0, stream>>>(
      pv_part0, pv_part1, wp2cT_hi, wp2cT_lo, whpT_hi, whpT_lo,
      b_p2c, bh_p, Wa_c, Wa_p, p_mask, ba_p, uh, pairC, score_p, g_arr, pv_sum);

  kd_scores<<<dim3(8192), dim3(256), 0, stream>>>(
      c_mask, p_mask, g_arr, pairC, pairP, score_c, score_p);

  ke_soft<<<dim3(320), dim3(256), 0, stream>>>(
      c, c_mask, p_mask, score_c, score_p, pv_sum, s_c, pf_part);

  kf_final<<<dim3(16), dim3(256), 0, stream>>>(
      s_c, wccv, b_comb_c, pf_part, W_comb_p, b_comb_p, out);
}

// Round 19
// 121.608 us; speedup vs baseline: 1.0204x; 1.0204x over previous
//
#include <hip/hip_runtime.h>

// BIATT: B=16, Lc=Lp=1024, D=128, H=4, PFEAT=1024. All inputs fp32.
// Algebra: cv is rank-1 (c[b,l]*cp[d]) => A = tanh(c[b,l]*g[b,h,m]);
// scores reduce to 1D sums over tanh of an outer product.
// R19 = restore R15 best config (121.6us): KA folds+transposes; KB pv GEMM
// (split-bf16, K-split x2) UNION c-side maps; KC weight-stationary 3-term
// split + g (2-buffer prefetch, 64-row tiles); KD fused tile tanh reduction
// (f32 T, conflict-free both passes); KE softmax+pools (4-chunk); KF finals.

using bf16x8 = __attribute__((ext_vector_type(8))) short;
using u16x8  = __attribute__((ext_vector_type(8))) unsigned short;
using f32x4  = __attribute__((ext_vector_type(4))) float;

#define TWO_LOG2E 2.8853900817779268f

__device__ __forceinline__ float exp2_raw(float x){
#if __has_builtin(__builtin_amdgcn_exp2f)
  return __builtin_amdgcn_exp2f(x);
#else
  float r; asm("v_exp_f32 %0, %1" : "=v"(r) : "v"(x)); return r;
#endif
}
__device__ __forceinline__ float tanh_fast(float x){
  float e = exp2_raw(x * TWO_LOG2E);
  return fmaf(-2.0f, __builtin_amdgcn_rcpf(e + 1.0f), 1.0f);
}
__device__ __forceinline__ unsigned short f2bf(float f){
  unsigned u = __float_as_uint(f);
  u = (u + 0x7FFFu + ((u >> 16) & 1u)) >> 16; // RNE
  return (unsigned short)u;
}
__device__ __forceinline__ float bf2f(unsigned short s){
  return __uint_as_float((unsigned)s << 16);
}
__device__ __forceinline__ unsigned cvt_pk_bf16(float a, float b){
  unsigned r;
  asm("v_cvt_pk_bf16_f32 %0, %1, %2" : "=v"(r) : "v"(a), "v"(b));
  return r;
}
// split 8 f32 -> hi/lo bf16x8 fragments (lo = x - hi is exact in f32)
__device__ __forceinline__ void split8(const float4& x, const float4& y, bf16x8& hi, bf16x8& lo){
  unsigned h0 = cvt_pk_bf16(x.x, x.y);
  unsigned h1 = cvt_pk_bf16(x.z, x.w);
  unsigned h2 = cvt_pk_bf16(y.x, y.y);
  unsigned h3 = cvt_pk_bf16(y.z, y.w);
  float r0 = x.x - __uint_as_float(h0 << 16);
  float r1 = x.y - __uint_as_float(h0 & 0xffff0000u);
  float r2 = x.z - __uint_as_float(h1 << 16);
  float r3 = x.w - __uint_as_float(h1 & 0xffff0000u);
  float r4 = y.x - __uint_as_float(h2 << 16);
  float r5 = y.y - __uint_as_float(h2 & 0xffff0000u);
  float r6 = y.z - __uint_as_float(h3 << 16);
  float r7 = y.w - __uint_as_float(h3 & 0xffff0000u);
  uint4 H = make_uint4(h0, h1, h2, h3);
  uint4 L = make_uint4(cvt_pk_bf16(r0, r1), cvt_pk_bf16(r2, r3),
                       cvt_pk_bf16(r4, r5), cvt_pk_bf16(r6, r7));
  hi = __builtin_bit_cast(bf16x8, H);
  lo = __builtin_bit_cast(bf16x8, L);
}

// ---------------------------------------------------------------- KA: param folds (bid<4) + transposes (bid>=4)
__global__ __launch_bounds__(256) void ka_prep(
    const float* __restrict__ c_param,
    const float* __restrict__ U, const float* __restrict__ W_comb_c,
    const float* __restrict__ Wh_c, const float* __restrict__ W_c2p,
    const float* __restrict__ p_param, const float* __restrict__ W_p2c,
    const float* __restrict__ Wh_p,
    float* __restrict__ uh, float* __restrict__ wccv,
    float* __restrict__ whc_v, float* __restrict__ wc2p_v,
    unsigned short* __restrict__ ppT_hi, unsigned short* __restrict__ ppT_lo,
    unsigned short* __restrict__ wp2cT_hi, unsigned short* __restrict__ wp2cT_lo,
    unsigned short* __restrict__ whpT_hi, unsigned short* __restrict__ whpT_lo)
{
  __shared__ float T[64*68];
  int bid0 = blockIdx.x, t = threadIdx.x;
  if (bid0 < 4) {
    int h = bid0;
    if (t < 128) {
      float s_uh = 0.f, s_wcc = 0.f, s_whc = 0.f, s_wc2p = 0.f;
      for (int d = 0; d < 128; ++d) {
        float cp = c_param[d];
        s_uh   += cp * U[(h*128 + d)*128 + t];
        s_wcc  += cp * W_comb_c[(h*128 + d)*128 + t];
        s_whc  += cp * Wh_c[(h*128 + d)*128 + t];
        s_wc2p += cp * W_c2p[(h*128 + d)*128 + t];
      }
      uh[h*128 + t]     = s_uh;
      wccv[h*128 + t]   = s_wcc;
      whc_v[h*128 + t]  = s_whc;
      wc2p_v[h*128 + t] = s_wc2p;
    }
    return;
  }
  int bid = bid0 - 4;
  const float* src; unsigned short* dh; unsigned short* dl;
  int k0, e0, dpitch, drow0;
  if (bid < 32) {
    k0 = (bid >> 1)*64; e0 = (bid & 1)*64;
    src = p_param; dh = ppT_hi; dl = ppT_lo; dpitch = 1024; drow0 = e0;
  } else if (bid < 48) {
    int w = bid - 32; int h = w >> 2, ki = (w >> 1) & 1, ej = w & 1;
    k0 = ki*64; e0 = ej*64;
    src = W_p2c + h*16384; dh = wp2cT_hi; dl = wp2cT_lo; dpitch = 128;
    drow0 = h*128 + e0;
  } else {
    int w = bid - 48; int h = w >> 2, ki = (w >> 1) & 1, ej = w & 1;
    k0 = ki*64; e0 = ej*64;
    src = Wh_p + h*16384; dh = whpT_hi; dl = whpT_lo; dpitch = 128;
    drow0 = h*128 + e0;
  }
  {
    int r = t >> 2, cs = (t & 3)*4;
    const float* s = src + (k0 + r)*128 + e0 + cs;
    #pragma unroll
    for (int j = 0; j < 4; ++j) {
      float4 v = *(const float4*)(s + j*16);
      *(float4*)&T[r*68 + cs + j*16] = v;
    }
  }
  __syncthreads();
  {
    int e = t >> 2, ks = (t & 3)*16;
    unsigned short hs[16], ls[16];
    #pragma unroll
    for (int j = 0; j < 16; ++j) {
      float v = T[(ks + j)*68 + e];
      unsigned short hh = f2bf(v);
      hs[j] = hh; ls[j] = f2bf(v - bf2f(hh));
    }
    unsigned short* ph = dh + (drow0 + e)*dpitch + k0 + ks;
    unsigned short* pl = dl + (drow0 + e)*dpitch + k0 + ks;
    *(u16x8*)ph       = *(u16x8*)&hs[0];
    *(u16x8*)(ph + 8) = *(u16x8*)&hs[8];
    *(u16x8*)pl       = *(u16x8*)&ls[0];
    *(u16x8*)(pl + 8) = *(u16x8*)&ls[8];
  }
}

// ---------------------------------------------------------------- KB: pv GEMM (bid<512, K-split x2) UNION c-side maps
__global__ __launch_bounds__(256) void kb_pv_maps(
    const float* __restrict__ p,
    const unsigned short* __restrict__ ppT_hi, const unsigned short* __restrict__ ppT_lo,
    float* __restrict__ pv_part0, float* __restrict__ pv_part1,
    const float* __restrict__ c, const float* __restrict__ c_mask,
    const float* __restrict__ whc_v, const float* __restrict__ wc2p_v,
    const float* __restrict__ bh_c, const float* __restrict__ b_c2p,
    const float* __restrict__ Wa_c, const float* __restrict__ Wa_p,
    const float* __restrict__ ba_c,
    float* __restrict__ score_c, float2* __restrict__ pairP)
{
  __shared__ __align__(16) char smem[36864];
  int bid = blockIdx.x, t = threadIdx.x;
  if (bid < 512) {
    short* Bh = (short*)smem;              // [128*72]
    short* Bl = (short*)(smem + 18432);
    int khalf = bid >> 8, rowtile = bid & 255;
    int kbase = khalf * 512;
    int row0 = rowtile * 64;
    float* __restrict__ pvp = khalf ? pv_part1 : pv_part0;
    int w = t >> 6, lane = t & 63;
    int l15 = lane & 15, l4 = lane >> 4;

    int bcol = t >> 1, bkh = (t & 1) * 32;
    const unsigned short* gBh = ppT_hi + bcol*1024 + kbase + bkh;
    const unsigned short* gBl = ppT_lo + bcol*1024 + kbase + bkh;
    short* sBh = &Bh[bcol*72 + bkh];
    short* sBl = &Bl[bcol*72 + bkh];

    const float* gA = p + (row0 + w*16 + l15)*1024 + kbase + l4*8;

    u16x8 rb[8];
    float4 ra[4];

    #pragma unroll
    for (int j = 0; j < 4; ++j) {
      rb[j]   = *(const u16x8*)(gBh + j*8);
      rb[4+j] = *(const u16x8*)(gBl + j*8);
    }
    #pragma unroll
    for (int j = 0; j < 4; ++j)
      ra[j] = *(const float4*)(gA + (j>>1)*32 + (j&1)*4);

    f32x4 acc[8];
    #pragma unroll
    for (int n = 0; n < 8; ++n) acc[n] = (f32x4){0.f,0.f,0.f,0.f};

    for (int kc = 0; kc < 8; ++kc) {
      __syncthreads();
      #pragma unroll
      for (int j = 0; j < 4; ++j) {
        *(u16x8*)(sBh + j*8) = rb[j];
        *(u16x8*)(sBl + j*8) = rb[4+j];
      }
      if (kc < 7) {
        #pragma unroll
        for (int j = 0; j < 4; ++j) {
          rb[j]   = *(const u16x8*)(gBh + (kc+1)*64 + j*8);
          rb[4+j] = *(const u16x8*)(gBl + (kc+1)*64 + j*8);
        }
      }
      float4 ran0, ran1, ran2, ran3;
      if (kc < 7) {
        const float* gAn = gA + (kc+1)*64;
        ran0 = *(const float4*)(gAn);
        ran1 = *(const float4*)(gAn + 4);
        ran2 = *(const float4*)(gAn + 32);
        ran3 = *(const float4*)(gAn + 36);
      }
      __syncthreads();
      #pragma unroll
      for (int ks = 0; ks < 2; ++ks) {
        bf16x8 ah, al;
        split8(ra[2*ks], ra[2*ks+1], ah, al);
        #pragma unroll
        for (int ct = 0; ct < 8; ++ct) {
          bf16x8 bh = *(const bf16x8*)&Bh[(ct*16 + l15)*72 + ks*32 + l4*8];
          bf16x8 bl = *(const bf16x8*)&Bl[(ct*16 + l15)*72 + ks*32 + l4*8];
          acc[ct] = __builtin_amdgcn_mfma_f32_16x16x32_bf16(ah, bh, acc[ct], 0, 0, 0);
          acc[ct] = __builtin_amdgcn_mfma_f32_16x16x32_bf16(ah, bl, acc[ct], 0, 0, 0);
          acc[ct] = __builtin_amdgcn_mfma_f32_16x16x32_bf16(al, bh, acc[ct], 0, 0, 0);
        }
      }
      if (kc < 7) { ra[0] = ran0; ra[1] = ran1; ra[2] = ran2; ra[3] = ran3; }
    }

    #pragma unroll
    for (int ct = 0; ct < 8; ++ct) {
      int col = ct*16 + l15;
      #pragma unroll
      for (int r = 0; r < 4; ++r) {
        int row = row0 + w*16 + l4*4 + r;
        pvp[row*128 + col] = acc[ct][r];
      }
    }
  } else {
    float* fsh = (float*)smem;  // 6 x 128 floats
    float* whc_l  = fsh;
    float* wc2p_l = fsh + 128;
    float* bhc_l  = fsh + 256;
    float* bc2p_l = fsh + 384;
    float* wac1_l = fsh + 512;
    float* wap2_l = fsh + 640;
    int i = bid - 512;
    int b = i >> 4, h = (i >> 2) & 3, lc = i & 3;
    if (t < 128) {
      whc_l[t]  = whc_v[h*128 + t];
      wc2p_l[t] = wc2p_v[h*128 + t];
      bhc_l[t]  = bh_c[h*128 + t];
      bc2p_l[t] = b_c2p[h*128 + t];
      wac1_l[t] = Wa_c[h*256 + t];
      wap2_l[t] = Wa_p[h*256 + 128 + t];
    }
    __syncthreads();
    int l = lc*256 + t;
    float cl = c[b*1024 + l];
    float a1 = 0.f, a2 = 0.f;
    #pragma unroll 4
    for (int e = 0; e < 128; ++e) {
      a1 += wac1_l[e] * tanh_fast(cl*whc_l[e]  + bhc_l[e]);
      a2 += wap2_l[e] * tanh_fast(cl*wc2p_l[e] + bc2p_l[e]);
    }
    int o = (b*4 + h)*1024 + l;
    score_c[o] = a1 + ba_c[h];
    pairP[o] = make_float2(TWO_LOG2E * cl, c_mask[b*1024 + l] * a2);
  }
}

// ---------------------------------------------------------------- KC: weight-stationary per-(path,h), 3-term split + g
// grid 2048: bid = ph*256 + mtile (64 rows); 256%8==0 -> pv tile XCD-local.
__global__ __launch_bounds__(256) void kc_head(
    const float* __restrict__ pv0, const float* __restrict__ pv1,
    const unsigned short* __restrict__ wp2cT_hi, const unsigned short* __restrict__ wp2cT_lo,
    const unsigned short* __restrict__ whpT_hi, const unsigned short* __restrict__ whpT_lo,
    const float* __restrict__ b_p2c, const float* __restrict__ bh_p,
    const float* __restrict__ Wa_c, const float* __restrict__ Wa_p,
    const float* __restrict__ p_mask, const float* __restrict__ ba_p,
    const float* __restrict__ uh,
    float2* __restrict__ pairC, float* __restrict__ score_p,
    float* __restrict__ g_arr, float* __restrict__ pv_sum)
{
  __shared__ __align__(16) short Whs[64*136];
  __shared__ __align__(16) short Wls[64*136];
  int t = threadIdx.x;
  int bid = blockIdx.x;
  int ph = bid >> 8, mtile = bid & 255;
  int path = ph >> 2, h = ph & 3;
  int w = t >> 6, lane = t & 63;
  int l15 = lane & 15, l4 = lane >> 4;

  const unsigned short* Wgh = (path ? whpT_hi : wp2cT_hi) + h*16384;
  const unsigned short* Wgl = (path ? whpT_lo : wp2cT_lo) + h*16384;
  int e2 = t >> 2, k0s = (t & 3)*32;

  // prefetch q0 weights into regs (overlaps A-load latency)
  u16x8 wr_h[4], wr_l[4];
  {
    const u16x8* sh = (const u16x8*)(Wgh + e2*128 + k0s);
    const u16x8* sl = (const u16x8*)(Wgl + e2*128 + k0s);
    #pragma unroll
    for (int j = 0; j < 4; ++j) { wr_h[j] = sh[j]; wr_l[j] = sl[j]; }
  }

  const float* bias_g = path ? bh_p : b_p2c;
  float biasv[8], wav[8];
  #pragma unroll
  for (int n = 0; n < 8; ++n) {
    int col = n*16 + l15;
    biasv[n] = bias_g[h*128 + col];
    wav[n]   = path ? Wa_p[h*256 + col] : Wa_c[h*256 + 128 + col];
  }

  int rowbase = mtile*64 + w*16;
  bf16x8 afh[4], afl[4];
  float gacc = 0.f;
  {
    int off = (rowbase + l15)*128 + l4*8;
    #pragma unroll
    for (int kt = 0; kt < 4; ++kt) {
      float4 x0 = *(const float4*)(pv0 + off + kt*32);
      float4 y0 = *(const float4*)(pv0 + off + kt*32 + 4);
      float4 x1 = *(const float4*)(pv1 + off + kt*32);
      float4 y1 = *(const float4*)(pv1 + off + kt*32 + 4);
      float4 x = make_float4(x0.x+x1.x, x0.y+x1.y, x0.z+x1.z, x0.w+x1.w);
      float4 y = make_float4(y0.x+y1.x, y0.y+y1.y, y0.z+y1.z, y0.w+y1.w);
      if (ph == 0) {
        *(float4*)(pv_sum + off + kt*32)     = x;
        *(float4*)(pv_sum + off + kt*32 + 4) = y;
      }
      split8(x, y, afh[kt], afl[kt]);
      if (!path) {
        float4 u0 = *(const float4*)(uh + h*128 + kt*32 + l4*8);
        float4 u1 = *(const float4*)(uh + h*128 + kt*32 + l4*8 + 4);
        gacc += x.x*u0.x + x.y*u0.y + x.z*u0.z + x.w*u0.w
              + y.x*u1.x + y.y*u1.y + y.z*u1.z + y.w*u1.w;
      }
    }
  }
  if (!path) {
    float gg = gacc;
    gg += __shfl_xor(gg, 16, 64);
    gg += __shfl_xor(gg, 32, 64);
    if (l4 == 0) {
      int grow = rowbase + l15;
      int bb = grow >> 10, m = grow & 1023;
      int idx = (bb*4 + h)*1024 + m;
      g_arr[idx] = gg;
      pairC[idx].x = TWO_LOG2E * gg;
    }
  }

  f32x4 acc[8];
  #pragma unroll
  for (int n = 0; n < 8; ++n) acc[n] = (f32x4){0.f,0.f,0.f,0.f};

  // write q0 stage
  {
    u16x8* dhh = (u16x8*)&Whs[e2*136 + k0s];
    u16x8* dll = (u16x8*)&Wls[e2*136 + k0s];
    #pragma unroll
    for (int j = 0; j < 4; ++j) { dhh[j] = wr_h[j]; dll[j] = wr_l[j]; }
  }
  __syncthreads();
  // prefetch q1 (overlaps q0 MFMA)
  {
    const u16x8* sh = (const u16x8*)(Wgh + (64 + e2)*128 + k0s);
    const u16x8* sl = (const u16x8*)(Wgl + (64 + e2)*128 + k0s);
    #pragma unroll
    for (int j = 0; j < 4; ++j) { wr_h[j] = sh[j]; wr_l[j] = sl[j]; }
  }
  // MFMA q0
  #pragma unroll
  for (int n = 0; n < 4; ++n) {
    #pragma unroll
    for (int kt = 0; kt < 4; ++kt) {
      bf16x8 bh = *(const bf16x8*)&Whs[(n*16 + l15)*136 + kt*32 + l4*8];
      bf16x8 bl = *(const bf16x8*)&Wls[(n*16 + l15)*136 + kt*32 + l4*8];
      acc[n] = __builtin_amdgcn_mfma_f32_16x16x32_bf16(afh[kt], bh, acc[n], 0, 0, 0);
      acc[n] = __builtin_amdgcn_mfma_f32_16x16x32_bf16(afh[kt], bl, acc[n], 0, 0, 0);
      acc[n] = __builtin_amdgcn_mfma_f32_16x16x32_bf16(afl[kt], bh, acc[n], 0, 0, 0);
    }
  }
  __syncthreads();
  // write q1 stage
  {
    u16x8* dhh = (u16x8*)&Whs[e2*136 + k0s];
    u16x8* dll = (u16x8*)&Wls[e2*136 + k0s];
    #pragma unroll
    for (int j = 0; j < 4; ++j) { dhh[j] = wr_h[j]; dll[j] = wr_l[j]; }
  }
  __syncthreads();
  // MFMA q1
  #pragma unroll
  for (int n = 0; n < 4; ++n) {
    int nn = 4 + n;
    #pragma unroll
    for (int kt = 0; kt < 4; ++kt) {
      bf16x8 bh = *(const bf16x8*)&Whs[(n*16 + l15)*136 + kt*32 + l4*8];
      bf16x8 bl = *(const bf16x8*)&Wls[(n*16 + l15)*136 + kt*32 + l4*8];
      acc[nn] = __builtin_amdgcn_mfma_f32_16x16x32_bf16(afh[kt], bh, acc[nn], 0, 0, 0);
      acc[nn] = __builtin_amdgcn_mfma_f32_16x16x32_bf16(afh[kt], bl, acc[nn], 0, 0, 0);
      acc[nn] = __builtin_amdgcn_mfma_f32_16x16x32_bf16(afl[kt], bh, acc[nn], 0, 0, 0);
    }
  }

  {
    float pp0 = 0.f, pp1 = 0.f, pp2 = 0.f, pp3 = 0.f;
    #pragma unroll
    for (int n = 0; n < 8; ++n) {
      float bb = biasv[n], ww = wav[n];
      pp0 += ww * tanh_fast(acc[n][0] + bb);
      pp1 += ww * tanh_fast(acc[n][1] + bb);
      pp2 += ww * tanh_fast(acc[n][2] + bb);
      pp3 += ww * tanh_fast(acc[n][3] + bb);
    }
    #pragma unroll
    for (int off = 1; off < 16; off <<= 1) {
      pp0 += __shfl_xor(pp0, off, 64);
      pp1 += __shfl_xor(pp1, off, 64);
      pp2 += __shfl_xor(pp2, off, 64);
      pp3 += __shfl_xor(pp3, off, 64);
    }
    if (l15 == 0) {
      int grow = rowbase + l4*4;
      int bb = grow >> 10, m = grow & 1023;
      int idx = (bb*4 + h)*1024 + m;
      if (path) {
        float bap = ba_p[h];
        *(float4*)&score_p[idx] = make_float4(pp0+bap, pp1+bap, pp2+bap, pp3+bap);
      } else {
        float4 mk = *(const float4*)&p_mask[bb*1024 + m];
        pairC[idx+0].y = mk.x * pp0;
        pairC[idx+1].y = mk.y * pp1;
        pairC[idx+2].y = mk.z * pp2;
        pairC[idx+3].y = mk.w * pp3;
      }
    }
  }
}

// ---------------------------------------------------------------- KD: fused tile tanh reduction (T once, conflict-free)
// grid 8192: bid = bh*128 + tile; 128(l) x 64(m) per block.
__global__ __launch_bounds__(256) void kd_scores(
    const float* __restrict__ c_mask, const float* __restrict__ p_mask,
    const float* __restrict__ g_arr,
    const float2* __restrict__ pairC, const float2* __restrict__ pairP,
    float* __restrict__ score_c, float* __restrict__ score_p)
{
  __shared__ float T[128*65];
  __shared__ float gm_s[64], ptw_s[64], pm_s[64];
  __shared__ float kl_s[128], ctw_s[128], cm_s[128];
  __shared__ float red[256];
  int bid = blockIdx.x, t = threadIdx.x;
  int bh = bid >> 7, tile = bid & 127;
  int b = bh >> 2;
  int l0 = (tile >> 4) * 128, m0 = (tile & 15) * 64;
  if (t < 64) {
    gm_s[t]  = g_arr[bh*1024 + m0 + t];
    ptw_s[t] = pairC[bh*1024 + m0 + t].y;
    pm_s[t]  = p_mask[b*1024 + m0 + t];
  } else if (t < 192) {
    int l = t - 64;
    float2 pp = pairP[bh*1024 + l0 + l];
    kl_s[l] = pp.x; ctw_s[l] = pp.y;
    cm_s[l] = c_mask[b*1024 + l0 + l];
  }
  __syncthreads();
  { // pass 1: 2 threads per l-row, 32 m each; store T; row sums -> score_c
    int r = t >> 1, hm = t & 1;
    float kl = kl_s[r];
    float accc = 0.f;
    #pragma unroll 8
    for (int j = 0; j < 32; ++j) {
      int m = hm*32 + j;
      float e = exp2_raw(kl * gm_s[m]);           // exp(2 c_l g_m)
      float tt = fmaf(-2.0f, __builtin_amdgcn_rcpf(e + 1.0f), 1.0f);
      T[r*65 + m] = tt;
      accc = fmaf(ptw_s[m], tt, accc);
    }
    accc += __shfl_xor(accc, 1, 64);
    if (hm == 0) atomicAdd(score_c + bh*1024 + l0 + r, cm_s[r]*accc);
  }
  __syncthreads();
  { // pass 2: col = t&63 (full wave spans 64 cols -> 2-way banks, free)
    int col = t & 63, seg = t >> 6;
    float accp = 0.f;
    #pragma unroll 8
    for (int j = 0; j < 32; ++j) {
      int l = seg*32 + j;
      accp = fmaf(ctw_s[l], T[l*65 + col], accp);
    }
    red[t] = accp;
    __syncthreads();
    if (t < 64) {
      float total = red[t] + red[t+64] + red[t+128] + red[t+192];
      atomicAdd(score_p + bh*1024 + m0 + t, pm_s[t]*total);
    }
  }
}

// ---------------------------------------------------------------- KE: softmax + pools (p-side 4-way chunked)
__device__ __forceinline__ float blk_red_max(float v, float* red, int t){
  red[t] = v; __syncthreads();
  for (int s = 128; s; s >>= 1) { if (t < s) red[t] = fmaxf(red[t], red[t+s]); __syncthreads(); }
  float r = red[0]; __syncthreads();
  return r;
}
__device__ __forceinline__ float blk_red_sum(float v, float* red, int t){
  red[t] = v; __syncthreads();
  for (int s = 128; s; s >>= 1) { if (t < s) red[t] += red[t+s]; __syncthreads(); }
  float r = red[0]; __syncthreads();
  return r;
}

__global__ __launch_bounds__(256) void ke_soft(
    const float* __restrict__ c, const float* __restrict__ c_mask, const float* __restrict__ p_mask,
    const float* __restrict__ score_c, const float* __restrict__ score_p,
    const float* __restrict__ pv_sum,
    float* __restrict__ s_c, float* __restrict__ pf_part)
{
  __shared__ float sv[1024];
  __shared__ float red[256];
  int bid = blockIdx.x, t = threadIdx.x;
  if (bid < 64) { // c-side
    int b = bid >> 2, h = bid & 3, bh = b*4 + h;
    const float* sc = score_c + bh*1024;
    const float* mk = c_mask + b*1024;
    float v[4];
    float mx = -1e30f;
    #pragma unroll
    for (int j = 0; j < 4; ++j) { v[j] = sc[t + j*256]; mx = fmaxf(mx, v[j]); }
    mx = blk_red_max(mx, red, t);
    float sum = 0.f;
    #pragma unroll
    for (int j = 0; j < 4; ++j) {
      float e = exp2_raw((v[j] - mx) * 1.4426950408889634f) * mk[t + j*256];
      sv[t + j*256] = e;
      sum += e;
    }
    sum = blk_red_sum(sum, red, t);
    float rinv = __fdividef(1.0f, sum + 1e-6f);
    float a = 0.f;
    #pragma unroll
    for (int j = 0; j < 4; ++j) a += sv[t + j*256] * rinv * c[b*1024 + t + j*256];
    a = blk_red_sum(a, red, t);
    if (t == 0) s_c[bh] = a;
  } else { // p-side, 4 chunks per (b,h)
    int i = bid - 64;
    int b = i >> 4, h = (i >> 2) & 3, ch = i & 3, bh = b*4 + h;
    const float* sc = score_p + bh*1024;
    const float* mk = p_mask + b*1024;
    float v[4];
    float mx = -1e30f;
    #pragma unroll
    for (int j = 0; j < 4; ++j) { v[j] = sc[t + j*256]; mx = fmaxf(mx, v[j]); }
    mx = blk_red_max(mx, red, t);
    float sum = 0.f;
    #pragma unroll
    for (int j = 0; j < 4; ++j) {
      float e = exp2_raw((v[j] - mx) * 1.4426950408889634f) * mk[t + j*256];
      sv[t + j*256] = e;
      sum += e;
    }
    sum = blk_red_sum(sum, red, t);
    float rinv = __fdividef(1.0f, sum + 1e-6f);
    int e0 = t & 127, seg = t >> 7;
    int mbase = ch*256 + seg*128;
    float acc = 0.f;
    const float* base = pv_sum + (b*1024 + mbase)*128 + e0;
    #pragma unroll 4
    for (int m = 0; m < 128; ++m) acc = fmaf(sv[mbase + m]*rinv, base[m*128], acc);
    red[t] = acc; __syncthreads();
    if (t < 128) pf_part[(ch*16 + b)*512 + h*128 + t] = red[t] + red[t + 128];
  }
}

// ---------------------------------------------------------------- KF: finals + outer product (sums pool chunks)
__global__ __launch_bounds__(256) void kf_final(
    const float* __restrict__ s_c, const float* __restrict__ wccv,
    const float* __restrict__ b_comb_c, const float* __restrict__ pf_part,
    const float* __restrict__ W_comb_p, const float* __restrict__ b_comb_p,
    float* __restrict__ out)
{
  __shared__ float pfr[512];
  __shared__ float cfl[128], pfl[128];
  int b = blockIdx.x, t = threadIdx.x;
  #pragma unroll
  for (int s = 0; s < 2; ++s) {
    int idx = t + s*256;
    pfr[idx] = pf_part[(0*16 + b)*512 + idx] + pf_part[(1*16 + b)*512 + idx]
             + pf_part[(2*16 + b)*512 + idx] + pf_part[(3*16 + b)*512 + idx];
  }
  __syncthreads();
  if (t < 128) {
    float cf = b_comb_c[t];
    #pragma unroll
    for (int h = 0; h < 4; ++h) cf += s_c[b*4 + h] * wccv[h*128 + t];
    float pf = b_comb_p[t];
    #pragma unroll 8
    for (int i = 0; i < 512; ++i) pf += pfr[i] * W_comb_p[i*128 + t];
    cfl[t] = cf; pfl[t] = pf;
  }
  __syncthreads();
  #pragma unroll
  for (int k = 0; k < 64; ++k) {
    int idx = k*256 + t;
    out[b*16384 + idx] = cfl[idx >> 7] * pfl[idx & 127];
  }
}

// ---------------------------------------------------------------- launcher
extern "C" void kernel_launch(void* const* d_in, const int* in_sizes, int n_in,
                              void* d_out, int out_size, void* d_ws, size_t ws_size,
                              hipStream_t stream)
{
  const float* c        = (const float*)d_in[0];
  const float* c_mask   = (const float*)d_in[1];
  const float* p        = (const float*)d_in[2];
  const float* p_mask   = (const float*)d_in[3];
  const float* c_param  = (const float*)d_in[4];
  const float* p_param  = (const float*)d_in[5];
  const float* U        = (const float*)d_in[6];
  const float* W_p2c    = (const float*)d_in[7];
  const float* b_p2c    = (const float*)d_in[8];
  const float* W_c2p    = (const float*)d_in[9];
  const float* b_c2p    = (const float*)d_in[10];
  const float* Wh_c     = (const float*)d_in[11];
  const float* bh_c     = (const float*)d_in[12];
  const float* Wh_p     = (const float*)d_in[13];
  const float* bh_p     = (const float*)d_in[14];
  const float* Wa_c     = (const float*)d_in[15];
  const float* ba_c     = (const float*)d_in[16];
  const float* Wa_p     = (const float*)d_in[17];
  const float* ba_p     = (const float*)d_in[18];
  const float* W_comb_c = (const float*)d_in[19];
  const float* b_comb_c = (const float*)d_in[20];
  const float* W_comb_p = (const float*)d_in[21];
  const float* b_comb_p = (const float*)d_in[22];
  float* out = (float*)d_out;

  char* ws = (char*)d_ws;
  float*          pv_part0 = (float*)         (ws + 0);
  float*          pv_part1 = (float*)         (ws + 8388608);
  float*          pv_sum   = (float*)         (ws + 16777216);
  unsigned short* ppT_hi   = (unsigned short*)(ws + 25165824);
  unsigned short* ppT_lo   = (unsigned short*)(ws + 25427968);
  unsigned short* wp2cT_hi = (unsigned short*)(ws + 25690112);
  unsigned short* wp2cT_lo = (unsigned short*)(ws + 25821184);
  unsigned short* whpT_hi  = (unsigned short*)(ws + 25952256);
  unsigned short* whpT_lo  = (unsigned short*)(ws + 26083328);
  float*          uh       = (float*)         (ws + 26214400);
  float*          wccv     = (float*)         (ws + 26216448);
  float*          whc_v    = (float*)         (ws + 26218496);
  float*          wc2p_v   = (float*)         (ws + 26220544);
  float*          g_arr    = (float*)         (ws + 26222592);
  float2*         pairC    = (float2*)        (ws + 26484736);
  float2*         pairP    = (float2*)        (ws + 27009024);
  float*          score_c  = (float*)         (ws + 27533312);
  float*          score_p  = (float*)         (ws + 27795456);
  float*          s_c      = (float*)         (ws + 28057600);
  float*          pf_part  = (float*)         (ws + 28057856);

  ka_prep<<<dim3(68), dim3(256), 0, stream>>>(
      c_param, U, W_comb_c, Wh_c, W_c2p, p_param, W_p2c, Wh_p,
      uh, wccv, whc_v, wc2p_v,
      ppT_hi, ppT_lo, wp2cT_hi, wp2cT_lo, whpT_hi, whpT_lo);

  kb_pv_maps<<<dim3(768), dim3(256), 0, stream>>>(
      p, ppT_hi, ppT_lo, pv_part0, pv_part1,
      c, c_mask, whc_v, wc2p_v, bh_c, b_c2p, Wa_c, Wa_p, ba_c,
      score_c, pairP);

  kc_head<<<dim3(2048), dim3(256), 0, stream>>>(
      pv_part0, pv_part1, wp2cT_hi, wp2cT_lo, whpT_hi, whpT_lo,
      b_p2c, bh_p, Wa_c, Wa_p, p_mask, ba_p, uh, pairC, score_p, g_arr, pv_sum);

  kd_scores<<<dim3(8192), dim3(256), 0, stream>>>(
      c_mask, p_mask, g_arr, pairC, pairP, score_c, score_p);

  ke_soft<<<dim3(320), dim3(256), 0, stream>>>(
      c, c_mask, p_mask, score_c, score_p, pv_sum, s_c, pf_part);

  kf_final<<<dim3(16), dim3(256), 0, stream>>>(
      s_c, wccv, b_comb_c, pf_part, W_comb_p, b_comb_p, out);
}